// Round 11
// baseline (25192.401 us; speedup 1.0000x reference)
//
#include <hip/hip_runtime.h>

#define TT   2048
#define NB   32
#define NI   512
#define NHID 512
#define NWG  32
#define KSL  16   // h-columns owned per workgroup

typedef float    f32x4 __attribute__((ext_vector_type(4)));
typedef float    f32x2 __attribute__((ext_vector_type(2)));
typedef _Float16 f16x8 __attribute__((ext_vector_type(8)));

// flags[0..63]: flags[2w+half] = t+1 when (block w, batch-half) h-slice stored.
// flags[64] = xcc mask, flags[65] = arrival count (placement check).
__device__ __align__(256) unsigned int g_flags[80];
__device__ __align__(256) _Float16    g_hb0[NB * NHID];
__device__ __align__(256) _Float16    g_hb1[NB * NHID];

__device__ __forceinline__ f16x8 pack8(f32x4 a, f32x4 b) {
    f16x8 r;
    r[0] = (_Float16)a[0]; r[1] = (_Float16)a[1]; r[2] = (_Float16)a[2]; r[3] = (_Float16)a[3];
    r[4] = (_Float16)b[0]; r[5] = (_Float16)b[1]; r[6] = (_Float16)b[2]; r[7] = (_Float16)b[3];
    return r;
}

__device__ __forceinline__ unsigned int poll_load_nt(const unsigned int* p) {
    unsigned int v;
    asm volatile("global_load_dword %0, %1, off nt\n\ts_waitcnt vmcnt(0)"
                 : "=v"(v) : "v"(p) : "memory");
    return v;
}

extern "C" __global__ void init_flags_k() {
    if (threadIdx.x < 80) g_flags[threadIdx.x] = 0u;
}

// Zero-barrier persistent GRU (round-10 worker structure, bit-identical) PLUS
// waves 4-7 = continuous FMA spinners co-resident on the SAME CUs (2 waves/SIMD)
// for the whole kernel, exiting via an LDS done counter. This is the clean
// per-XCD DVFS test: round-8 heated only other XCDs (and VGPR-capped workers);
// round-9's spinners ran ~1% of the time. Critical-path arithmetic (2200 cy)
// vs measured 9.6us/step implies SCLK parked at ~250 MHz.
extern "C" __global__ void __launch_bounds__(512, 1)
gru_persist(const float* __restrict__ X, const float* __restrict__ h0,
            const float* __restrict__ Wih, const float* __restrict__ Whh,
            const float* __restrict__ bih, const float* __restrict__ bhh,
            const float* __restrict__ Wd,  const float* __restrict__ bd,
            float* __restrict__ out)
{
    if (blockIdx.x & 7) return;
    const int w  = blockIdx.x >> 3;
    const int ks = w * KSL;

    __shared__ float gi_lds[2][2][4][16][16]; // [parity][half][r,z,n,dense][b_loc][k_loc]
    __shared__ float bias_h[3][KSL];          // bhh r,z,n (own k)
    __shared__ float bias_i[4][KSL];          // bih r,z,n + b_dense (own k)
    __shared__ unsigned int seq[8];           // [half]=prod_seq, [2+half]=cons_seq, [4]=done
    __shared__ unsigned int fast_sh;
    volatile unsigned int* vseq = seq;

    const int tid  = threadIdx.x;
    const int lane = tid & 63;
    const int wv   = tid >> 6;
    const int half = wv & 1;
    const int isp  = wv >> 1;      // 0=consumer, 1=producer, >=2=spinner
    const int r15  = lane & 15;
    const int g4   = lane >> 4;

    if (tid < 8) seq[tid] = 0u;
    if (tid < KSL) {
        int k = ks + tid;
        bias_h[0][tid] = bhh[k];
        bias_h[1][tid] = bhh[512 + k];
        bias_h[2][tid] = bhh[1024 + k];
        bias_i[0][tid] = bih[k];
        bias_i[1][tid] = bih[512 + k];
        bias_i[2][tid] = bih[1024 + k];
        bias_i[3][tid] = bd[k];
    }
    if (tid == 0) {
        unsigned int xcc;
        asm volatile("s_getreg_b32 %0, hwreg(HW_REG_XCC_ID, 0, 32)" : "=s"(xcc));
        unsigned int bit = 1u << (xcc & 7);
        unsigned int* mask  = g_flags + 64;
        unsigned int* count = g_flags + 65;
        unsigned int old = __hip_atomic_fetch_or(mask, bit, __ATOMIC_RELAXED,
                                                 __HIP_MEMORY_SCOPE_AGENT);
        asm volatile("" :: "v"(old));
        __hip_atomic_fetch_add(count, 1u, __ATOMIC_RELAXED, __HIP_MEMORY_SCOPE_AGENT);
        while (__hip_atomic_load(count, __ATOMIC_RELAXED,
                                 __HIP_MEMORY_SCOPE_AGENT) < NWG) { }
        unsigned int m = __hip_atomic_load(mask, __ATOMIC_RELAXED,
                                           __HIP_MEMORY_SCOPE_AGENT);
        fast_sh = ((m & (m - 1)) == 0) ? 1u : 0u;
    }
    __syncthreads();
    const bool fast = (fast_sh != 0);

    if (isp >= 2) {
        // ================= SPINNERS (waves 4-7): continuous XCD-local DVFS load
        __builtin_amdgcn_s_setprio(0);
        float s0 = 1.00f + (float)tid, s1 = s0 + .1f, s2 = s0 + .2f, s3 = s0 + .3f;
        float s4 = s0 + .4f, s5 = s0 + .5f, s6 = s0 + .6f, s7 = s0 + .7f;
        const float mm = 1.0000001f, cc = 1.0e-7f;
        while (vseq[4] < 2u) {
            #pragma unroll
            for (int i = 0; i < 64; ++i) {
                s0 = __builtin_fmaf(s0, mm, cc); s1 = __builtin_fmaf(s1, mm, cc);
                s2 = __builtin_fmaf(s2, mm, cc); s3 = __builtin_fmaf(s3, mm, cc);
                s4 = __builtin_fmaf(s4, mm, cc); s5 = __builtin_fmaf(s5, mm, cc);
                s6 = __builtin_fmaf(s6, mm, cc); s7 = __builtin_fmaf(s7, mm, cc);
            }
        }
        asm volatile("" :: "v"(s0), "v"(s1), "v"(s2), "v"(s3),
                          "v"(s4), "v"(s5), "v"(s6), "v"(s7));
        return;
    }

    if (!isp) {
        // ================= CONSUMER (waves 0,1) =================
        __builtin_amdgcn_s_setprio(1);
        const int bg = half * 16 + r15;            // my batch (via D col / B row)

        f16x8 A[3][16];                            // Whh fragments, rows ks+r15
        #pragma unroll
        for (int q = 0; q < 3; ++q) {
            const float* src = Whh + (size_t)(q * 512 + ks + r15) * NHID;
            #pragma unroll
            for (int kc = 0; kc < 16; ++kc) {
                const f32x4* p = (const f32x4*)(src + kc * 32 + g4 * 8);
                A[q][kc] = pack8(p[0], p[1]);
            }
        }
        f32x4 hold = *(const f32x4*)(h0 + (size_t)bg * NHID + ks + g4 * 4);
        const f32x4 bhr = *(const f32x4*)&bias_h[0][g4 * 4];
        const f32x4 bhz = *(const f32x4*)&bias_h[1][g4 * 4];
        const f32x4 bhn = *(const f32x4*)&bias_h[2][g4 * 4];
        const f32x4 bir = *(const f32x4*)&bias_i[0][g4 * 4];
        const f32x4 biz = *(const f32x4*)&bias_i[1][g4 * 4];
        const f32x4 bin = *(const f32x4*)&bias_i[2][g4 * 4];
        const f32x4 bd4 = *(const f32x4*)&bias_i[3][g4 * 4];

        const float* h0row = h0 + (size_t)bg * NHID;

        #pragma unroll 1
        for (int t = 0; t < TT; ++t) {
            // -- 1. cross-block wait: the 32 flags of MY half
            if (t > 0 && lane < NWG) {
                const unsigned int* fp = &g_flags[2 * lane + half];
                if (fast) { while (poll_load_nt(fp) < (unsigned)t) { } }
                else      { while (__hip_atomic_load(fp, __ATOMIC_RELAXED,
                                       __HIP_MEMORY_SCOPE_AGENT) < (unsigned)t) { } }
            }
            // -- 2. load h_t fragment
            f16x8 Bf[16];
            if (t == 0) {
                #pragma unroll
                for (int kc = 0; kc < 16; ++kc) {
                    const f32x4* p = (const f32x4*)(h0row + kc * 32 + g4 * 8);
                    Bf[kc] = pack8(p[0], p[1]);
                }
            } else {
                const _Float16* hrow = ((t & 1) ? g_hb1 : g_hb0) + (size_t)bg * NHID;
                if (fast) {
                    #pragma unroll
                    for (int kc = 0; kc < 16; ++kc) {
                        const _Float16* p = hrow + kc * 32 + g4 * 8;
                        asm volatile("global_load_dwordx4 %0, %1, off nt"
                                     : "=v"(Bf[kc]) : "v"(p));
                    }
                } else {
                    #pragma unroll
                    for (int kc = 0; kc < 16; ++kc) {
                        const _Float16* p = hrow + kc * 32 + g4 * 8;
                        asm volatile("global_load_dwordx4 %0, %1, off sc0 sc1"
                                     : "=v"(Bf[kc]) : "v"(p));
                    }
                }
                asm volatile("s_waitcnt vmcnt(0)" ::: "memory");
                __builtin_amdgcn_sched_barrier(0);
            }
            // -- 3. gh MFMA (acc[reg] = gh[k=ks+g4*4+reg][b=bg])
            f32x4 a0 = {0.f,0.f,0.f,0.f}, a1 = a0, a2 = a0;
            #pragma unroll
            for (int kc = 0; kc < 16; ++kc) {
                a0 = __builtin_amdgcn_mfma_f32_16x16x32_f16(A[0][kc], Bf[kc], a0, 0, 0, 0);
                a1 = __builtin_amdgcn_mfma_f32_16x16x32_f16(A[1][kc], Bf[kc], a1, 0, 0, 0);
                a2 = __builtin_amdgcn_mfma_f32_16x16x32_f16(A[2][kc], Bf[kc], a2, 0, 0, 0);
            }
            // -- 4. gi ready? read it, release the parity slot
            while (vseq[half] < (unsigned)(t + 1)) { }
            const int par = t & 1;
            f32x4 gr = *(const f32x4*)&gi_lds[par][half][0][r15][g4 * 4];
            f32x4 gz = *(const f32x4*)&gi_lds[par][half][1][r15][g4 * 4];
            f32x4 gn = *(const f32x4*)&gi_lds[par][half][2][r15][g4 * 4];
            f32x4 gd = *(const f32x4*)&gi_lds[par][half][3][r15][g4 * 4];
            asm volatile("s_waitcnt lgkmcnt(0)" ::: "memory");
            if (lane == 0) vseq[2 + half] = (unsigned)(t + 1);
            // -- 5. gates in-register
            f32x4 hn, o;
            #pragma unroll
            for (int i = 0; i < 4; ++i) {
                float rr = 1.f / (1.f + __expf(-((gr[i] + bir[i]) + (a0[i] + bhr[i]))));
                float zz = 1.f / (1.f + __expf(-((gz[i] + biz[i]) + (a1[i] + bhz[i]))));
                float aa = (gn[i] + bin[i]) + rr * (a2[i] + bhn[i]);
                float nn = 1.f - 2.f / (__expf(2.f * aa) + 1.f);
                hn[i] = (1.f - zz) * nn + zz * hold[i];
                o[i]  = hn[i] + gd[i] + bd4[i];
            }
            hold = hn;
            // -- 6. h broadcast store (4 fp16 = 8B, consecutive k)
            union { _Float16 h[4]; unsigned long long u; } cv;
            cv.h[0] = (_Float16)hn[0]; cv.h[1] = (_Float16)hn[1];
            cv.h[2] = (_Float16)hn[2]; cv.h[3] = (_Float16)hn[3];
            _Float16* hw = (((t + 1) & 1) ? g_hb1 : g_hb0) + (size_t)bg * NHID + ks + g4 * 4;
            if (fast) {
                *(unsigned long long*)hw = cv.u;
            } else {
                asm volatile("global_store_dwordx2 %0, %1, off sc0 sc1"
                             :: "v"(hw), "v"(cv.u) : "memory");
            }
            // -- 7. drain h store, publish own flag
            asm volatile("s_waitcnt vmcnt(0)" ::: "memory");
            if (lane == 0) {
                unsigned int* fp = &g_flags[2 * w + half];
                if (fast) *(volatile unsigned int*)fp = (unsigned)(t + 1);
                else __hip_atomic_store(fp, (unsigned)(t + 1), __ATOMIC_RELAXED,
                                        __HIP_MEMORY_SCOPE_AGENT);
            }
            // -- 8. output store (off critical path, drains later)
            *(f32x4*)(out + (size_t)t * (NB * NHID) + (size_t)bg * NHID + ks + g4 * 4) = o;
        }
        // h_last
        *(f32x4*)(out + (size_t)TT * (NB * NHID) + (size_t)bg * NHID + ks + g4 * 4) = hold;
        // release this block's spinner waves (2 consumer waves -> done==2)
        if (lane == 0)
            __hip_atomic_fetch_add((unsigned int*)&seq[4], 1u, __ATOMIC_RELAXED,
                                   __HIP_MEMORY_SCOPE_WORKGROUP);
    } else {
        // ================= PRODUCER (waves 2,3) =================
        f16x8 A[4][16];                            // Wih r,z,n + Wd, rows ks+r15
        #pragma unroll
        for (int q = 0; q < 4; ++q) {
            const float* src = (q < 3) ? (Wih + (size_t)(q * 512 + ks + r15) * NI)
                                       : (Wd  + (size_t)(ks + r15) * NI);
            #pragma unroll
            for (int kc = 0; kc < 16; ++kc) {
                const f32x4* p = (const f32x4*)(src + kc * 32 + g4 * 8);
                A[q][kc] = pack8(p[0], p[1]);
            }
        }
        const float* Xrow = X + (size_t)(half * 16 + r15) * NI;

        #pragma unroll 1
        for (int tp = 0; tp < TT; ++tp) {
            // throttle: 2-deep buffer -> need consumer to have consumed tp-2
            while ((int)vseq[2 + half] < tp - 1) { }
            const float* xp = Xrow + (size_t)tp * (NB * NI);
            f16x8 Bf[16];
            #pragma unroll
            for (int kc = 0; kc < 16; ++kc) {
                const f32x4* p = (const f32x4*)(xp + kc * 32 + g4 * 8);
                Bf[kc] = pack8(p[0], p[1]);
            }
            f32x4 a0 = {0.f,0.f,0.f,0.f}, a1 = a0, a2 = a0, a3 = a0;
            #pragma unroll
            for (int kc = 0; kc < 16; ++kc) {
                a0 = __builtin_amdgcn_mfma_f32_16x16x32_f16(A[0][kc], Bf[kc], a0, 0, 0, 0);
                a1 = __builtin_amdgcn_mfma_f32_16x16x32_f16(A[1][kc], Bf[kc], a1, 0, 0, 0);
                a2 = __builtin_amdgcn_mfma_f32_16x16x32_f16(A[2][kc], Bf[kc], a2, 0, 0, 0);
                a3 = __builtin_amdgcn_mfma_f32_16x16x32_f16(A[3][kc], Bf[kc], a3, 0, 0, 0);
            }
            const int par = tp & 1;
            *(f32x4*)&gi_lds[par][half][0][r15][g4 * 4] = a0;
            *(f32x4*)&gi_lds[par][half][1][r15][g4 * 4] = a1;
            *(f32x4*)&gi_lds[par][half][2][r15][g4 * 4] = a2;
            *(f32x4*)&gi_lds[par][half][3][r15][g4 * 4] = a3;
            asm volatile("s_waitcnt lgkmcnt(0)" ::: "memory");
            if (lane == 0) vseq[half] = (unsigned)(tp + 1);
        }
    }
}

extern "C" void kernel_launch(void* const* d_in, const int* in_sizes, int n_in,
                              void* d_out, int out_size, void* d_ws, size_t ws_size,
                              hipStream_t stream) {
    const float* X   = (const float*)d_in[0];
    const float* h0  = (const float*)d_in[1];
    const float* Wih = (const float*)d_in[2];
    const float* Whh = (const float*)d_in[3];
    const float* bih = (const float*)d_in[4];
    const float* bhh = (const float*)d_in[5];
    const float* Wd  = (const float*)d_in[6];
    const float* bd  = (const float*)d_in[7];
    float* out = (float*)d_out;

    init_flags_k<<<dim3(1), dim3(128), 0, stream>>>();

    gru_persist<<<dim3(256), dim3(512), 0, stream>>>(
        X, h0, Wih, Whh, bih, bhh, Wd, bd, out);
}

// Round 12
// 15982.779 us; speedup vs baseline: 1.5762x; 1.5762x over previous
//
#include <hip/hip_runtime.h>

#define TT   2048
#define NB   32
#define NI   512
#define NHID 512
#define NWG  32
#define KSL  16   // h-columns owned per workgroup

typedef float    f32x4 __attribute__((ext_vector_type(4)));
typedef _Float16 f16x8 __attribute__((ext_vector_type(8)));

// g_flags[w*16 + half*8] = t+1 when (block w, batch-half) h-slice stored (64B pad).
// g_flags[512] = xcc mask, g_flags[513] = arrival count.
__device__ __align__(256) unsigned int g_flags[576];
__device__ __align__(256) _Float16    g_hb0[NB * NHID];
__device__ __align__(256) _Float16    g_hb1[NB * NHID];

__device__ __forceinline__ f16x8 pack8(f32x4 a, f32x4 b) {
    f16x8 r;
    r[0] = (_Float16)a[0]; r[1] = (_Float16)a[1]; r[2] = (_Float16)a[2]; r[3] = (_Float16)a[3];
    r[4] = (_Float16)b[0]; r[5] = (_Float16)b[1]; r[6] = (_Float16)b[2]; r[7] = (_Float16)b[3];
    return r;
}

__device__ __forceinline__ unsigned int poll_load_nt(const unsigned int* p) {
    unsigned int v;
    asm volatile("global_load_dword %0, %1, off nt\n\ts_waitcnt vmcnt(0)"
                 : "=v"(v) : "v"(p) : "memory");
    return v;
}

extern "C" __global__ void init_flags_k() {
    for (int i = threadIdx.x; i < 576; i += 256) g_flags[i] = 0u;
}

// Zero-barrier persistent GRU, SPILL-FREE edition.
// Root cause of the invariant ~17k-cycle step (r3-r11): A[3..4][16] f16x8 weight
// fragments = 192-256 VGPRs/wave -> compiler spilled them to scratch; ~48-64
// scratch reloads per step on the critical path. Fix: weights pre-packed ONCE
// into LDS as MFMA fragments (Whh 48KB + Wih 48KB), ds_read_b128 per MFMA.
// Also: out-stores moved to producer waves via LDS ring (consumer vmcnt only
// covers its 8B h-store); flags padded to 64B.
extern "C" __global__ void __launch_bounds__(256, 1)
gru_persist(const float* __restrict__ X, const float* __restrict__ h0,
            const float* __restrict__ Wih, const float* __restrict__ Whh,
            const float* __restrict__ bih, const float* __restrict__ bhh,
            const float* __restrict__ Wd,  const float* __restrict__ bd,
            float* __restrict__ out)
{
    if (blockIdx.x & 7) return;
    const int w  = blockIdx.x >> 3;
    const int ks = w * KSL;

    __shared__ _Float16 fragWhh[3][16][64][8];   // 48 KB: [gate][kc][lane][e]
    __shared__ _Float16 fragWih[3][16][64][8];   // 48 KB
    __shared__ float    gi_lds[2][2][4][16][16]; // 16 KB [parity][half][r,z,n,d][b][k]
    __shared__ f32x4    oring[4][2][64];         //  8 KB out ring [slot][half][lane]
    __shared__ float    bias_h[3][KSL];
    __shared__ float    bias_i[4][KSL];
    __shared__ unsigned int seq[8];  // 0,1 prod_seq; 2,3 cons_seq; 4,5 oseq; 6,7 odrain
    __shared__ unsigned int fast_sh;
    volatile unsigned int* vseq = seq;

    const int tid  = threadIdx.x;
    const int lane = tid & 63;
    const int wv   = tid >> 6;
    const int half = wv & 1;
    const int isp  = wv >> 1;      // 0 = consumer, 1 = producer
    const int r15  = lane & 15;
    const int g4   = lane >> 4;

    if (tid < 8) seq[tid] = 0u;
    if (tid < KSL) {
        int k = ks + tid;
        bias_h[0][tid] = bhh[k];
        bias_h[1][tid] = bhh[512 + k];
        bias_h[2][tid] = bhh[1024 + k];
        bias_i[0][tid] = bih[k];
        bias_i[1][tid] = bih[512 + k];
        bias_i[2][tid] = bih[1024 + k];
        bias_i[3][tid] = bd[k];
    }
    // ---- one-time: pack weight fragments into LDS (6 slots over 4 waves)
    for (int s = wv; s < 6; s += 4) {
        const float* src = (s < 3) ? (Whh + (size_t)(s * 512 + ks + r15) * NHID)
                                   : (Wih + (size_t)((s - 3) * 512 + ks + r15) * NI);
        #pragma unroll
        for (int kc = 0; kc < 16; ++kc) {
            const f32x4* p = (const f32x4*)(src + kc * 32 + g4 * 8);
            f16x8 v = pack8(p[0], p[1]);
            if (s < 3) *(f16x8*)&fragWhh[s][kc][lane][0] = v;
            else       *(f16x8*)&fragWih[s - 3][kc][lane][0] = v;
        }
    }
    if (tid == 0) {
        unsigned int xcc;
        asm volatile("s_getreg_b32 %0, hwreg(HW_REG_XCC_ID, 0, 32)" : "=s"(xcc));
        unsigned int bit = 1u << (xcc & 7);
        unsigned int* mask  = g_flags + 512;
        unsigned int* count = g_flags + 513;
        unsigned int old = __hip_atomic_fetch_or(mask, bit, __ATOMIC_RELAXED,
                                                 __HIP_MEMORY_SCOPE_AGENT);
        asm volatile("" :: "v"(old));
        __hip_atomic_fetch_add(count, 1u, __ATOMIC_RELAXED, __HIP_MEMORY_SCOPE_AGENT);
        while (__hip_atomic_load(count, __ATOMIC_RELAXED,
                                 __HIP_MEMORY_SCOPE_AGENT) < NWG) { }
        unsigned int m = __hip_atomic_load(mask, __ATOMIC_RELAXED,
                                           __HIP_MEMORY_SCOPE_AGENT);
        fast_sh = ((m & (m - 1)) == 0) ? 1u : 0u;
    }
    __syncthreads();
    const bool fast = (fast_sh != 0);
    const int  bg   = half * 16 + r15;   // batch owned by this lane (cons & prod out)

    if (!isp) {
        // ================= CONSUMER (waves 0,1) =================
        __builtin_amdgcn_s_setprio(1);
        f32x4 hold = *(const f32x4*)(h0 + (size_t)bg * NHID + ks + g4 * 4);
        const f32x4 bhr = *(const f32x4*)&bias_h[0][g4 * 4];
        const f32x4 bhz = *(const f32x4*)&bias_h[1][g4 * 4];
        const f32x4 bhn = *(const f32x4*)&bias_h[2][g4 * 4];
        const f32x4 bir = *(const f32x4*)&bias_i[0][g4 * 4];
        const f32x4 biz = *(const f32x4*)&bias_i[1][g4 * 4];
        const f32x4 bin = *(const f32x4*)&bias_i[2][g4 * 4];
        const f32x4 bd4 = *(const f32x4*)&bias_i[3][g4 * 4];
        const float* h0row = h0 + (size_t)bg * NHID;

        #pragma unroll 1
        for (int t = 0; t < TT; ++t) {
            // -- 1. cross-block wait (padded flags, 64B apart)
            if (t > 0 && lane < NWG) {
                const unsigned int* fp = &g_flags[lane * 16 + half * 8];
                if (fast) { while (poll_load_nt(fp) < (unsigned)t) { } }
                else      { while (__hip_atomic_load(fp, __ATOMIC_RELAXED,
                                       __HIP_MEMORY_SCOPE_AGENT) < (unsigned)t) { } }
            }
            // -- 2. load h_t fragment
            f16x8 Bf[16];
            if (t == 0) {
                #pragma unroll
                for (int kc = 0; kc < 16; ++kc) {
                    const f32x4* p = (const f32x4*)(h0row + kc * 32 + g4 * 8);
                    Bf[kc] = pack8(p[0], p[1]);
                }
            } else {
                const _Float16* hrow = ((t & 1) ? g_hb1 : g_hb0) + (size_t)bg * NHID;
                if (fast) {
                    #pragma unroll
                    for (int kc = 0; kc < 16; ++kc) {
                        const _Float16* p = hrow + kc * 32 + g4 * 8;
                        asm volatile("global_load_dwordx4 %0, %1, off nt"
                                     : "=v"(Bf[kc]) : "v"(p));
                    }
                } else {
                    #pragma unroll
                    for (int kc = 0; kc < 16; ++kc) {
                        const _Float16* p = hrow + kc * 32 + g4 * 8;
                        asm volatile("global_load_dwordx4 %0, %1, off sc0 sc1"
                                     : "=v"(Bf[kc]) : "v"(p));
                    }
                }
                asm volatile("s_waitcnt vmcnt(0)" ::: "memory");
                __builtin_amdgcn_sched_barrier(0);
            }
            // -- 3. gh MFMA, A-fragments streamed from LDS (no VGPR spills!)
            f32x4 a0 = {0.f,0.f,0.f,0.f}, a1 = a0, a2 = a0;
            #pragma unroll
            for (int kc = 0; kc < 16; ++kc) {
                f16x8 w0 = *(const f16x8*)&fragWhh[0][kc][lane][0];
                f16x8 w1 = *(const f16x8*)&fragWhh[1][kc][lane][0];
                f16x8 w2 = *(const f16x8*)&fragWhh[2][kc][lane][0];
                a0 = __builtin_amdgcn_mfma_f32_16x16x32_f16(w0, Bf[kc], a0, 0, 0, 0);
                a1 = __builtin_amdgcn_mfma_f32_16x16x32_f16(w1, Bf[kc], a1, 0, 0, 0);
                a2 = __builtin_amdgcn_mfma_f32_16x16x32_f16(w2, Bf[kc], a2, 0, 0, 0);
            }
            // -- 4. gi ready? read it, release the parity slot
            while (vseq[half] < (unsigned)(t + 1)) { }
            const int par = t & 1;
            f32x4 gr = *(const f32x4*)&gi_lds[par][half][0][r15][g4 * 4];
            f32x4 gz = *(const f32x4*)&gi_lds[par][half][1][r15][g4 * 4];
            f32x4 gn = *(const f32x4*)&gi_lds[par][half][2][r15][g4 * 4];
            f32x4 gd = *(const f32x4*)&gi_lds[par][half][3][r15][g4 * 4];
            asm volatile("s_waitcnt lgkmcnt(0)" ::: "memory");
            if (lane == 0) vseq[2 + half] = (unsigned)(t + 1);
            // -- 5. gates in-register
            f32x4 hn, o;
            #pragma unroll
            for (int i = 0; i < 4; ++i) {
                float rr = 1.f / (1.f + __expf(-((gr[i] + bir[i]) + (a0[i] + bhr[i]))));
                float zz = 1.f / (1.f + __expf(-((gz[i] + biz[i]) + (a1[i] + bhz[i]))));
                float aa = (gn[i] + bin[i]) + rr * (a2[i] + bhn[i]);
                float nn = 1.f - 2.f / (__expf(2.f * aa) + 1.f);
                hn[i] = (1.f - zz) * nn + zz * hold[i];
                o[i]  = hn[i] + gd[i] + bd4[i];
            }
            hold = hn;
            // -- 6. h broadcast store (8B) — the ONLY vmem op this wave waits on
            union { _Float16 h[4]; unsigned long long u; } cv;
            cv.h[0] = (_Float16)hn[0]; cv.h[1] = (_Float16)hn[1];
            cv.h[2] = (_Float16)hn[2]; cv.h[3] = (_Float16)hn[3];
            _Float16* hw = (((t + 1) & 1) ? g_hb1 : g_hb0) + (size_t)bg * NHID + ks + g4 * 4;
            if (fast) {
                *(unsigned long long*)hw = cv.u;
            } else {
                asm volatile("global_store_dwordx2 %0, %1, off sc0 sc1"
                             :: "v"(hw), "v"(cv.u) : "memory");
            }
            asm volatile("s_waitcnt vmcnt(0)" ::: "memory");
            // -- 7. publish own flag
            if (lane == 0) {
                unsigned int* fp = &g_flags[w * 16 + half * 8];
                if (fast) *(volatile unsigned int*)fp = (unsigned)(t + 1);
                else __hip_atomic_store(fp, (unsigned)(t + 1), __ATOMIC_RELAXED,
                                        __HIP_MEMORY_SCOPE_AGENT);
            }
            // -- 8. hand output to producer waves via LDS ring (no global store here)
            while ((int)t - (int)vseq[6 + half] >= 4) { }   // ring space
            oring[t & 3][half][lane] = o;
            asm volatile("s_waitcnt lgkmcnt(0)" ::: "memory");
            if (lane == 0) vseq[4 + half] = (unsigned)(t + 1);
        }
        // h_last
        *(f32x4*)(out + (size_t)TT * (NB * NHID) + (size_t)bg * NHID + ks + g4 * 4) = hold;
    } else {
        // ================= PRODUCER (waves 2,3) =================
        f16x8 A3[16];   // Wd fragments stay in registers (64 VGPR, fits)
        #pragma unroll
        for (int kc = 0; kc < 16; ++kc) {
            const f32x4* p = (const f32x4*)(Wd + (size_t)(ks + r15) * NI + kc * 32 + g4 * 8);
            A3[kc] = pack8(p[0], p[1]);
        }
        const float* Xrow = X + (size_t)bg * NI;
        unsigned int drained = 0;

        #pragma unroll 1
        for (int tp = 0; tp < TT; ++tp) {
            while ((int)vseq[2 + half] < tp - 1) { }   // 2-deep gi throttle
            const float* xp = Xrow + (size_t)tp * (NB * NI);
            f16x8 Bf[16];
            #pragma unroll
            for (int kc = 0; kc < 16; ++kc) {
                const f32x4* p = (const f32x4*)(xp + kc * 32 + g4 * 8);
                Bf[kc] = pack8(p[0], p[1]);
            }
            f32x4 a0 = {0.f,0.f,0.f,0.f}, a1 = a0, a2 = a0, a3 = a0;
            #pragma unroll
            for (int kc = 0; kc < 16; ++kc) {
                f16x8 w0 = *(const f16x8*)&fragWih[0][kc][lane][0];
                f16x8 w1 = *(const f16x8*)&fragWih[1][kc][lane][0];
                f16x8 w2 = *(const f16x8*)&fragWih[2][kc][lane][0];
                a0 = __builtin_amdgcn_mfma_f32_16x16x32_f16(w0, Bf[kc], a0, 0, 0, 0);
                a1 = __builtin_amdgcn_mfma_f32_16x16x32_f16(w1, Bf[kc], a1, 0, 0, 0);
                a2 = __builtin_amdgcn_mfma_f32_16x16x32_f16(w2, Bf[kc], a2, 0, 0, 0);
                a3 = __builtin_amdgcn_mfma_f32_16x16x32_f16(A3[kc], Bf[kc], a3, 0, 0, 0);
            }
            const int par = tp & 1;
            *(f32x4*)&gi_lds[par][half][0][r15][g4 * 4] = a0;
            *(f32x4*)&gi_lds[par][half][1][r15][g4 * 4] = a1;
            *(f32x4*)&gi_lds[par][half][2][r15][g4 * 4] = a2;
            *(f32x4*)&gi_lds[par][half][3][r15][g4 * 4] = a3;
            asm volatile("s_waitcnt lgkmcnt(0)" ::: "memory");
            if (lane == 0) vseq[half] = (unsigned)(tp + 1);
            // drain out-ring (off the consumer's critical path)
            unsigned int s = vseq[4 + half];
            while (drained < s) {
                f32x4 o = oring[drained & 3][half][lane];
                *(f32x4*)(out + (size_t)drained * (NB * NHID)
                              + (size_t)bg * NHID + ks + g4 * 4) = o;
                ++drained;
                if (lane == 0) vseq[6 + half] = drained;
                s = vseq[4 + half];
            }
        }
        // tail drain
        while (drained < TT) {
            while (vseq[4 + half] <= drained) { }
            f32x4 o = oring[drained & 3][half][lane];
            *(f32x4*)(out + (size_t)drained * (NB * NHID)
                          + (size_t)bg * NHID + ks + g4 * 4) = o;
            ++drained;
            if (lane == 0) vseq[6 + half] = drained;
        }
    }
}

extern "C" void kernel_launch(void* const* d_in, const int* in_sizes, int n_in,
                              void* d_out, int out_size, void* d_ws, size_t ws_size,
                              hipStream_t stream) {
    const float* X   = (const float*)d_in[0];
    const float* h0  = (const float*)d_in[1];
    const float* Wih = (const float*)d_in[2];
    const float* Whh = (const float*)d_in[3];
    const float* bih = (const float*)d_in[4];
    const float* bhh = (const float*)d_in[5];
    const float* Wd  = (const float*)d_in[6];
    const float* bd  = (const float*)d_in[7];
    float* out = (float*)d_out;

    init_flags_k<<<dim3(1), dim3(256), 0, stream>>>();

    gru_persist<<<dim3(256), dim3(256), 0, stream>>>(
        X, h0, Wih, Whh, bih, bhh, Wd, bd, out);
}

// Round 13
// 15291.077 us; speedup vs baseline: 1.6475x; 1.0452x over previous
//
#include <hip/hip_runtime.h>

#define TT   2048
#define NB   32
#define NI   512
#define NHID 512
#define NWG  32
#define KSL  16   // h-columns owned per workgroup

typedef float    f32x4 __attribute__((ext_vector_type(4)));
typedef _Float16 f16x8 __attribute__((ext_vector_type(8)));

// g_flags[w*16 + half*8] = t+1 when (block w, batch-half) h-slice stored (64B pad).
// g_flags[512] = xcc mask, g_flags[513] = arrival count, g_flags[514] = done count.
__device__ __align__(256) unsigned int g_flags[576];
__device__ __align__(256) _Float16    g_hb0[NB * NHID];
__device__ __align__(256) _Float16    g_hb1[NB * NHID];

__device__ __forceinline__ f16x8 pack8(f32x4 a, f32x4 b) {
    f16x8 r;
    r[0] = (_Float16)a[0]; r[1] = (_Float16)a[1]; r[2] = (_Float16)a[2]; r[3] = (_Float16)a[3];
    r[4] = (_Float16)b[0]; r[5] = (_Float16)b[1]; r[6] = (_Float16)b[2]; r[7] = (_Float16)b[3];
    return r;
}

__device__ __forceinline__ unsigned int poll_load_nt(const unsigned int* p) {
    unsigned int v;
    asm volatile("global_load_dword %0, %1, off nt\n\ts_waitcnt vmcnt(0)"
                 : "=v"(v) : "v"(p) : "memory");
    return v;
}

extern "C" __global__ void init_flags_k() {
    for (int i = threadIdx.x; i < 576; i += 256) g_flags[i] = 0u;
}

// Round-12 spill-free worker (bit-identical) + SEPARATE-BLOCK spinners.
// Factorial history: r11 = spinners+spills (slow), r12 = no-spills+no-spinners
// (slow). This is the missing cell: no-spills + continuous co-resident spinners.
// Spinner blocks (bid>=256): 0 LDS, ~24 VGPR -> co-reside with the 123KB-LDS
// worker blocks on the same CUs; dense FMA at setprio(0) until done==64.
// If parked-SCLK theory holds (chain ~2-2.5k cy vs measured ~9.4us/step
// => ~250-300MHz), heating the chip recovers 3-6x.
extern "C" __global__ void __launch_bounds__(256, 1)
gru_persist(const float* __restrict__ X, const float* __restrict__ h0,
            const float* __restrict__ Wih, const float* __restrict__ Whh,
            const float* __restrict__ bih, const float* __restrict__ bhh,
            const float* __restrict__ Wd,  const float* __restrict__ bd,
            float* __restrict__ out)
{
    if (blockIdx.x >= 256) {
        // ================= SPINNER BLOCKS: continuous chip-wide DVFS load
        __builtin_amdgcn_s_setprio(0);
        unsigned int* done = g_flags + 514;
        float s0 = 1.0f + (float)threadIdx.x, s1 = s0 + .1f, s2 = s0 + .2f, s3 = s0 + .3f;
        float s4 = s0 + .4f, s5 = s0 + .5f, s6 = s0 + .6f, s7 = s0 + .7f;
        const float mm = 1.0000001f, cc = 1.0e-7f;
        while (__hip_atomic_load(done, __ATOMIC_RELAXED,
                                 __HIP_MEMORY_SCOPE_AGENT) < 64u) {
            #pragma unroll 32
            for (int i = 0; i < 2048; ++i) {
                s0 = __builtin_fmaf(s0, mm, cc); s1 = __builtin_fmaf(s1, mm, cc);
                s2 = __builtin_fmaf(s2, mm, cc); s3 = __builtin_fmaf(s3, mm, cc);
                s4 = __builtin_fmaf(s4, mm, cc); s5 = __builtin_fmaf(s5, mm, cc);
                s6 = __builtin_fmaf(s6, mm, cc); s7 = __builtin_fmaf(s7, mm, cc);
            }
        }
        asm volatile("" :: "v"(s0), "v"(s1), "v"(s2), "v"(s3),
                          "v"(s4), "v"(s5), "v"(s6), "v"(s7));
        return;
    }
    if (blockIdx.x & 7) return;
    const int w  = blockIdx.x >> 3;
    const int ks = w * KSL;

    __shared__ _Float16 fragWhh[3][16][64][8];   // 48 KB: [gate][kc][lane][e]
    __shared__ _Float16 fragWih[3][16][64][8];   // 48 KB
    __shared__ float    gi_lds[2][2][4][16][16]; // 16 KB [parity][half][r,z,n,d][b][k]
    __shared__ f32x4    oring[4][2][64];         //  8 KB out ring [slot][half][lane]
    __shared__ float    bias_h[3][KSL];
    __shared__ float    bias_i[4][KSL];
    __shared__ unsigned int seq[8];  // 0,1 prod_seq; 2,3 cons_seq; 4,5 oseq; 6,7 odrain
    __shared__ unsigned int fast_sh;
    volatile unsigned int* vseq = seq;

    const int tid  = threadIdx.x;
    const int lane = tid & 63;
    const int wv   = tid >> 6;
    const int half = wv & 1;
    const int isp  = wv >> 1;      // 0 = consumer, 1 = producer
    const int r15  = lane & 15;
    const int g4   = lane >> 4;

    if (tid < 8) seq[tid] = 0u;
    if (tid < KSL) {
        int k = ks + tid;
        bias_h[0][tid] = bhh[k];
        bias_h[1][tid] = bhh[512 + k];
        bias_h[2][tid] = bhh[1024 + k];
        bias_i[0][tid] = bih[k];
        bias_i[1][tid] = bih[512 + k];
        bias_i[2][tid] = bih[1024 + k];
        bias_i[3][tid] = bd[k];
    }
    // ---- one-time: pack weight fragments into LDS (6 slots over 4 waves)
    for (int s = wv; s < 6; s += 4) {
        const float* src = (s < 3) ? (Whh + (size_t)(s * 512 + ks + r15) * NHID)
                                   : (Wih + (size_t)((s - 3) * 512 + ks + r15) * NI);
        #pragma unroll
        for (int kc = 0; kc < 16; ++kc) {
            const f32x4* p = (const f32x4*)(src + kc * 32 + g4 * 8);
            f16x8 v = pack8(p[0], p[1]);
            if (s < 3) *(f16x8*)&fragWhh[s][kc][lane][0] = v;
            else       *(f16x8*)&fragWih[s - 3][kc][lane][0] = v;
        }
    }
    if (tid == 0) {
        unsigned int xcc;
        asm volatile("s_getreg_b32 %0, hwreg(HW_REG_XCC_ID, 0, 32)" : "=s"(xcc));
        unsigned int bit = 1u << (xcc & 7);
        unsigned int* mask  = g_flags + 512;
        unsigned int* count = g_flags + 513;
        unsigned int old = __hip_atomic_fetch_or(mask, bit, __ATOMIC_RELAXED,
                                                 __HIP_MEMORY_SCOPE_AGENT);
        asm volatile("" :: "v"(old));
        __hip_atomic_fetch_add(count, 1u, __ATOMIC_RELAXED, __HIP_MEMORY_SCOPE_AGENT);
        while (__hip_atomic_load(count, __ATOMIC_RELAXED,
                                 __HIP_MEMORY_SCOPE_AGENT) < NWG) { }
        unsigned int m = __hip_atomic_load(mask, __ATOMIC_RELAXED,
                                           __HIP_MEMORY_SCOPE_AGENT);
        fast_sh = ((m & (m - 1)) == 0) ? 1u : 0u;
    }
    __syncthreads();
    const bool fast = (fast_sh != 0);
    const int  bg   = half * 16 + r15;   // batch owned by this lane (cons & prod out)

    if (!isp) {
        // ================= CONSUMER (waves 0,1) =================
        __builtin_amdgcn_s_setprio(1);
        f32x4 hold = *(const f32x4*)(h0 + (size_t)bg * NHID + ks + g4 * 4);
        const f32x4 bhr = *(const f32x4*)&bias_h[0][g4 * 4];
        const f32x4 bhz = *(const f32x4*)&bias_h[1][g4 * 4];
        const f32x4 bhn = *(const f32x4*)&bias_h[2][g4 * 4];
        const f32x4 bir = *(const f32x4*)&bias_i[0][g4 * 4];
        const f32x4 biz = *(const f32x4*)&bias_i[1][g4 * 4];
        const f32x4 bin = *(const f32x4*)&bias_i[2][g4 * 4];
        const f32x4 bd4 = *(const f32x4*)&bias_i[3][g4 * 4];
        const float* h0row = h0 + (size_t)bg * NHID;

        #pragma unroll 1
        for (int t = 0; t < TT; ++t) {
            // -- 1. cross-block wait (padded flags, 64B apart)
            if (t > 0 && lane < NWG) {
                const unsigned int* fp = &g_flags[lane * 16 + half * 8];
                if (fast) { while (poll_load_nt(fp) < (unsigned)t) { } }
                else      { while (__hip_atomic_load(fp, __ATOMIC_RELAXED,
                                       __HIP_MEMORY_SCOPE_AGENT) < (unsigned)t) { } }
            }
            // -- 2. load h_t fragment
            f16x8 Bf[16];
            if (t == 0) {
                #pragma unroll
                for (int kc = 0; kc < 16; ++kc) {
                    const f32x4* p = (const f32x4*)(h0row + kc * 32 + g4 * 8);
                    Bf[kc] = pack8(p[0], p[1]);
                }
            } else {
                const _Float16* hrow = ((t & 1) ? g_hb1 : g_hb0) + (size_t)bg * NHID;
                if (fast) {
                    #pragma unroll
                    for (int kc = 0; kc < 16; ++kc) {
                        const _Float16* p = hrow + kc * 32 + g4 * 8;
                        asm volatile("global_load_dwordx4 %0, %1, off nt"
                                     : "=v"(Bf[kc]) : "v"(p));
                    }
                } else {
                    #pragma unroll
                    for (int kc = 0; kc < 16; ++kc) {
                        const _Float16* p = hrow + kc * 32 + g4 * 8;
                        asm volatile("global_load_dwordx4 %0, %1, off sc0 sc1"
                                     : "=v"(Bf[kc]) : "v"(p));
                    }
                }
                asm volatile("s_waitcnt vmcnt(0)" ::: "memory");
                __builtin_amdgcn_sched_barrier(0);
            }
            // -- 3. gh MFMA, A-fragments streamed from LDS (no VGPR spills)
            f32x4 a0 = {0.f,0.f,0.f,0.f}, a1 = a0, a2 = a0;
            #pragma unroll
            for (int kc = 0; kc < 16; ++kc) {
                f16x8 w0 = *(const f16x8*)&fragWhh[0][kc][lane][0];
                f16x8 w1 = *(const f16x8*)&fragWhh[1][kc][lane][0];
                f16x8 w2 = *(const f16x8*)&fragWhh[2][kc][lane][0];
                a0 = __builtin_amdgcn_mfma_f32_16x16x32_f16(w0, Bf[kc], a0, 0, 0, 0);
                a1 = __builtin_amdgcn_mfma_f32_16x16x32_f16(w1, Bf[kc], a1, 0, 0, 0);
                a2 = __builtin_amdgcn_mfma_f32_16x16x32_f16(w2, Bf[kc], a2, 0, 0, 0);
            }
            // -- 4. gi ready? read it, release the parity slot
            while (vseq[half] < (unsigned)(t + 1)) { }
            const int par = t & 1;
            f32x4 gr = *(const f32x4*)&gi_lds[par][half][0][r15][g4 * 4];
            f32x4 gz = *(const f32x4*)&gi_lds[par][half][1][r15][g4 * 4];
            f32x4 gn = *(const f32x4*)&gi_lds[par][half][2][r15][g4 * 4];
            f32x4 gd = *(const f32x4*)&gi_lds[par][half][3][r15][g4 * 4];
            asm volatile("s_waitcnt lgkmcnt(0)" ::: "memory");
            if (lane == 0) vseq[2 + half] = (unsigned)(t + 1);
            // -- 5. gates in-register
            f32x4 hn, o;
            #pragma unroll
            for (int i = 0; i < 4; ++i) {
                float rr = 1.f / (1.f + __expf(-((gr[i] + bir[i]) + (a0[i] + bhr[i]))));
                float zz = 1.f / (1.f + __expf(-((gz[i] + biz[i]) + (a1[i] + bhz[i]))));
                float aa = (gn[i] + bin[i]) + rr * (a2[i] + bhn[i]);
                float nn = 1.f - 2.f / (__expf(2.f * aa) + 1.f);
                hn[i] = (1.f - zz) * nn + zz * hold[i];
                o[i]  = hn[i] + gd[i] + bd4[i];
            }
            hold = hn;
            // -- 6. h broadcast store (8B) — the ONLY vmem op this wave waits on
            union { _Float16 h[4]; unsigned long long u; } cv;
            cv.h[0] = (_Float16)hn[0]; cv.h[1] = (_Float16)hn[1];
            cv.h[2] = (_Float16)hn[2]; cv.h[3] = (_Float16)hn[3];
            _Float16* hw = (((t + 1) & 1) ? g_hb1 : g_hb0) + (size_t)bg * NHID + ks + g4 * 4;
            if (fast) {
                *(unsigned long long*)hw = cv.u;
            } else {
                asm volatile("global_store_dwordx2 %0, %1, off sc0 sc1"
                             :: "v"(hw), "v"(cv.u) : "memory");
            }
            asm volatile("s_waitcnt vmcnt(0)" ::: "memory");
            // -- 7. publish own flag
            if (lane == 0) {
                unsigned int* fp = &g_flags[w * 16 + half * 8];
                if (fast) *(volatile unsigned int*)fp = (unsigned)(t + 1);
                else __hip_atomic_store(fp, (unsigned)(t + 1), __ATOMIC_RELAXED,
                                        __HIP_MEMORY_SCOPE_AGENT);
            }
            // -- 8. hand output to producer waves via LDS ring (no global store here)
            while ((int)t - (int)vseq[6 + half] >= 4) { }   // ring space
            oring[t & 3][half][lane] = o;
            asm volatile("s_waitcnt lgkmcnt(0)" ::: "memory");
            if (lane == 0) vseq[4 + half] = (unsigned)(t + 1);
        }
        // h_last
        *(f32x4*)(out + (size_t)TT * (NB * NHID) + (size_t)bg * NHID + ks + g4 * 4) = hold;
        // release spinner blocks (64 consumer waves total across the grid)
        if (lane == 0)
            __hip_atomic_fetch_add(g_flags + 514, 1u, __ATOMIC_RELAXED,
                                   __HIP_MEMORY_SCOPE_AGENT);
    } else {
        // ================= PRODUCER (waves 2,3) =================
        __builtin_amdgcn_s_setprio(1);
        f16x8 A3[16];   // Wd fragments stay in registers (64 VGPR, fits)
        #pragma unroll
        for (int kc = 0; kc < 16; ++kc) {
            const f32x4* p = (const f32x4*)(Wd + (size_t)(ks + r15) * NI + kc * 32 + g4 * 8);
            A3[kc] = pack8(p[0], p[1]);
        }
        const float* Xrow = X + (size_t)bg * NI;
        unsigned int drained = 0;

        #pragma unroll 1
        for (int tp = 0; tp < TT; ++tp) {
            while ((int)vseq[2 + half] < tp - 1) { }   // 2-deep gi throttle
            const float* xp = Xrow + (size_t)tp * (NB * NI);
            f16x8 Bf[16];
            #pragma unroll
            for (int kc = 0; kc < 16; ++kc) {
                const f32x4* p = (const f32x4*)(xp + kc * 32 + g4 * 8);
                Bf[kc] = pack8(p[0], p[1]);
            }
            f32x4 a0 = {0.f,0.f,0.f,0.f}, a1 = a0, a2 = a0, a3 = a0;
            #pragma unroll
            for (int kc = 0; kc < 16; ++kc) {
                f16x8 w0 = *(const f16x8*)&fragWih[0][kc][lane][0];
                f16x8 w1 = *(const f16x8*)&fragWih[1][kc][lane][0];
                f16x8 w2 = *(const f16x8*)&fragWih[2][kc][lane][0];
                a0 = __builtin_amdgcn_mfma_f32_16x16x32_f16(w0, Bf[kc], a0, 0, 0, 0);
                a1 = __builtin_amdgcn_mfma_f32_16x16x32_f16(w1, Bf[kc], a1, 0, 0, 0);
                a2 = __builtin_amdgcn_mfma_f32_16x16x32_f16(w2, Bf[kc], a2, 0, 0, 0);
                a3 = __builtin_amdgcn_mfma_f32_16x16x32_f16(A3[kc], Bf[kc], a3, 0, 0, 0);
            }
            const int par = tp & 1;
            *(f32x4*)&gi_lds[par][half][0][r15][g4 * 4] = a0;
            *(f32x4*)&gi_lds[par][half][1][r15][g4 * 4] = a1;
            *(f32x4*)&gi_lds[par][half][2][r15][g4 * 4] = a2;
            *(f32x4*)&gi_lds[par][half][3][r15][g4 * 4] = a3;
            asm volatile("s_waitcnt lgkmcnt(0)" ::: "memory");
            if (lane == 0) vseq[half] = (unsigned)(tp + 1);
            // drain out-ring (off the consumer's critical path)
            unsigned int s = vseq[4 + half];
            while (drained < s) {
                f32x4 o = oring[drained & 3][half][lane];
                *(f32x4*)(out + (size_t)drained * (NB * NHID)
                              + (size_t)bg * NHID + ks + g4 * 4) = o;
                ++drained;
                if (lane == 0) vseq[6 + half] = drained;
                s = vseq[4 + half];
            }
        }
        // tail drain
        while (drained < TT) {
            while (vseq[4 + half] <= drained) { }
            f32x4 o = oring[drained & 3][half][lane];
            *(f32x4*)(out + (size_t)drained * (NB * NHID)
                          + (size_t)bg * NHID + ks + g4 * 4) = o;
            ++drained;
            if (lane == 0) vseq[6 + half] = drained;
        }
    }
}

extern "C" void kernel_launch(void* const* d_in, const int* in_sizes, int n_in,
                              void* d_out, int out_size, void* d_ws, size_t ws_size,
                              hipStream_t stream) {
    const float* X   = (const float*)d_in[0];
    const float* h0  = (const float*)d_in[1];
    const float* Wih = (const float*)d_in[2];
    const float* Whh = (const float*)d_in[3];
    const float* bih = (const float*)d_in[4];
    const float* bhh = (const float*)d_in[5];
    const float* Wd  = (const float*)d_in[6];
    const float* bd  = (const float*)d_in[7];
    float* out = (float*)d_out;

    init_flags_k<<<dim3(1), dim3(256), 0, stream>>>();

    gru_persist<<<dim3(512), dim3(256), 0, stream>>>(
        X, h0, Wih, Whh, bih, bhh, Wd, bd, out);
}

// Round 14
// 10253.762 us; speedup vs baseline: 2.4569x; 1.4913x over previous
//
#include <hip/hip_runtime.h>

#define TT   2048
#define NB   32
#define NI   512
#define NHID 512
#define NWG  32
#define KSL  16   // h-columns owned per workgroup

typedef float    f32x4 __attribute__((ext_vector_type(4)));
typedef _Float16 f16x8 __attribute__((ext_vector_type(8)));

// g_flags[w*16 + half*8] = t+1 when (block w, batch-half) h-slice stored (64B pad).
// [512]=xcc mask, [513]=arrival count, [514]=done count.
__device__ __align__(256) unsigned int g_flags[576];
__device__ __align__(256) _Float16    g_hb0[NB * NHID];
__device__ __align__(256) _Float16    g_hb1[NB * NHID];
// Pre-packed input-side weight fragments: [w][mat(Wih r,z,n + Wd)][kc][lane][e]. 4MB.
__device__ __align__(256) _Float16    g_wfrag[NWG][4][16][64][8];

__device__ __forceinline__ f16x8 pack8(f32x4 a, f32x4 b) {
    f16x8 r;
    r[0] = (_Float16)a[0]; r[1] = (_Float16)a[1]; r[2] = (_Float16)a[2]; r[3] = (_Float16)a[3];
    r[4] = (_Float16)b[0]; r[5] = (_Float16)b[1]; r[6] = (_Float16)b[2]; r[7] = (_Float16)b[3];
    return r;
}

__device__ __forceinline__ unsigned int poll_load_nt(const unsigned int* p) {
    unsigned int v;
    asm volatile("global_load_dword %0, %1, off nt\n\ts_waitcnt vmcnt(0)"
                 : "=v"(v) : "v"(p) : "memory");
    return v;
}

extern "C" __global__ void init_flags_k() {
    for (int i = threadIdx.x; i < 576; i += 256) g_flags[i] = 0u;
}

// Pack Wih(r,z,n)+Wd fragments for worker w into g_wfrag (one block per worker).
extern "C" __global__ void pack_wfrag_k(const float* __restrict__ Wih,
                                        const float* __restrict__ Wd) {
    const int w    = blockIdx.x;
    const int tid  = threadIdx.x;
    const int lane = tid & 63;
    const int mat  = tid >> 6;           // 0..3
    const int r15  = lane & 15;
    const int g4   = lane >> 4;
    const float* src = (mat < 3) ? (Wih + (size_t)(mat * 512 + w * KSL + r15) * NI)
                                 : (Wd  + (size_t)(w * KSL + r15) * NI);
    #pragma unroll
    for (int kc = 0; kc < 16; ++kc) {
        const f32x4* p = (const f32x4*)(src + kc * 32 + g4 * 8);
        *(f16x8*)&g_wfrag[w][mat][kc][lane][0] = pack8(p[0], p[1]);
    }
}

// Zero-barrier spill-free persistent GRU + TRULY co-resident spinners.
// Worker LDS cut to ~68KB (fragWih/Wd streamed from g_wfrag by producers) so
// spinner blocks of the SAME kernel (also 68KB) co-reside on worker CUs:
// the first clean per-XCD DVFS stimulus on XCD0 (r8/r9/r11/r13 all flawed:
// wrong XCDs / 1% duty / VGPR-cap spills / LDS blocked co-residency).
// gi_lds padded [16][20] (2-way conflict = free, was 16-way).
extern "C" __global__ void __launch_bounds__(256, 1)
gru_persist(const float* __restrict__ X, const float* __restrict__ h0,
            const float* __restrict__ Wih, const float* __restrict__ Whh,
            const float* __restrict__ bih, const float* __restrict__ bhh,
            const float* __restrict__ Wd,  const float* __restrict__ bd,
            float* __restrict__ out)
{
    if (blockIdx.x >= 256) {
        // ============ SPINNER BLOCKS: co-resident on every CU incl. workers
        __builtin_amdgcn_s_setprio(0);
        unsigned int* done = g_flags + 514;
        float s0 = 1.0f + (float)threadIdx.x, s1 = s0 + .1f, s2 = s0 + .2f, s3 = s0 + .3f;
        float s4 = s0 + .4f, s5 = s0 + .5f, s6 = s0 + .6f, s7 = s0 + .7f;
        const float mm = 1.0000001f, cc = 1.0e-7f;
        while (__hip_atomic_load(done, __ATOMIC_RELAXED,
                                 __HIP_MEMORY_SCOPE_AGENT) < 64u) {
            #pragma unroll 32
            for (int i = 0; i < 2048; ++i) {
                s0 = __builtin_fmaf(s0, mm, cc); s1 = __builtin_fmaf(s1, mm, cc);
                s2 = __builtin_fmaf(s2, mm, cc); s3 = __builtin_fmaf(s3, mm, cc);
                s4 = __builtin_fmaf(s4, mm, cc); s5 = __builtin_fmaf(s5, mm, cc);
                s6 = __builtin_fmaf(s6, mm, cc); s7 = __builtin_fmaf(s7, mm, cc);
            }
        }
        asm volatile("" :: "v"(s0), "v"(s1), "v"(s2), "v"(s3),
                          "v"(s4), "v"(s5), "v"(s6), "v"(s7));
        return;
    }
    if (blockIdx.x & 7) return;
    const int w  = blockIdx.x >> 3;
    const int ks = w * KSL;

    __shared__ _Float16 fragWhh[3][16][64][8];   // 48 KB
    __shared__ float    gi_lds[2][2][4][16][20]; // 20 KB, padded (2-way = free)
    __shared__ float    bias_h[3][KSL];
    __shared__ float    bias_i[4][KSL];
    __shared__ unsigned int seq[8];              // 0,1 prod_seq; 2,3 cons_seq
    __shared__ unsigned int fast_sh;
    volatile unsigned int* vseq = seq;

    const int tid  = threadIdx.x;
    const int lane = tid & 63;
    const int wv   = tid >> 6;
    const int half = wv & 1;
    const int isp  = wv >> 1;      // 0 = consumer, 1 = producer
    const int r15  = lane & 15;
    const int g4   = lane >> 4;

    if (tid < 8) seq[tid] = 0u;
    if (tid < KSL) {
        int k = ks + tid;
        bias_h[0][tid] = bhh[k];
        bias_h[1][tid] = bhh[512 + k];
        bias_h[2][tid] = bhh[1024 + k];
        bias_i[0][tid] = bih[k];
        bias_i[1][tid] = bih[512 + k];
        bias_i[2][tid] = bih[1024 + k];
        bias_i[3][tid] = bd[k];
    }
    // pack Whh fragments into LDS (3 gates over 4 waves)
    for (int s = wv; s < 3; s += 4) {
        const float* src = Whh + (size_t)(s * 512 + ks + r15) * NHID;
        #pragma unroll
        for (int kc = 0; kc < 16; ++kc) {
            const f32x4* p = (const f32x4*)(src + kc * 32 + g4 * 8);
            *(f16x8*)&fragWhh[s][kc][lane][0] = pack8(p[0], p[1]);
        }
    }
    if (tid == 0) {
        unsigned int xcc;
        asm volatile("s_getreg_b32 %0, hwreg(HW_REG_XCC_ID, 0, 32)" : "=s"(xcc));
        unsigned int bit = 1u << (xcc & 7);
        unsigned int* mask  = g_flags + 512;
        unsigned int* count = g_flags + 513;
        unsigned int old = __hip_atomic_fetch_or(mask, bit, __ATOMIC_RELAXED,
                                                 __HIP_MEMORY_SCOPE_AGENT);
        asm volatile("" :: "v"(old));
        __hip_atomic_fetch_add(count, 1u, __ATOMIC_RELAXED, __HIP_MEMORY_SCOPE_AGENT);
        while (__hip_atomic_load(count, __ATOMIC_RELAXED,
                                 __HIP_MEMORY_SCOPE_AGENT) < NWG) { }
        unsigned int m = __hip_atomic_load(mask, __ATOMIC_RELAXED,
                                           __HIP_MEMORY_SCOPE_AGENT);
        fast_sh = ((m & (m - 1)) == 0) ? 1u : 0u;
    }
    __syncthreads();
    const bool fast = (fast_sh != 0);
    const int  bg   = half * 16 + r15;

    if (!isp) {
        // ================= CONSUMER (waves 0,1) =================
        __builtin_amdgcn_s_setprio(1);
        f32x4 hold = *(const f32x4*)(h0 + (size_t)bg * NHID + ks + g4 * 4);
        const f32x4 bhr = *(const f32x4*)&bias_h[0][g4 * 4];
        const f32x4 bhz = *(const f32x4*)&bias_h[1][g4 * 4];
        const f32x4 bhn = *(const f32x4*)&bias_h[2][g4 * 4];
        const f32x4 bir = *(const f32x4*)&bias_i[0][g4 * 4];
        const f32x4 biz = *(const f32x4*)&bias_i[1][g4 * 4];
        const f32x4 bin = *(const f32x4*)&bias_i[2][g4 * 4];
        const f32x4 bd4 = *(const f32x4*)&bias_i[3][g4 * 4];
        const float* h0row = h0 + (size_t)bg * NHID;

        #pragma unroll 1
        for (int t = 0; t < TT; ++t) {
            // -- 1. cross-block wait
            if (t > 0 && lane < NWG) {
                const unsigned int* fp = &g_flags[lane * 16 + half * 8];
                if (fast) { while (poll_load_nt(fp) < (unsigned)t) { } }
                else      { while (__hip_atomic_load(fp, __ATOMIC_RELAXED,
                                       __HIP_MEMORY_SCOPE_AGENT) < (unsigned)t) { } }
            }
            // -- 2. load h_t fragment
            f16x8 Bf[16];
            if (t == 0) {
                #pragma unroll
                for (int kc = 0; kc < 16; ++kc) {
                    const f32x4* p = (const f32x4*)(h0row + kc * 32 + g4 * 8);
                    Bf[kc] = pack8(p[0], p[1]);
                }
            } else {
                const _Float16* hrow = ((t & 1) ? g_hb1 : g_hb0) + (size_t)bg * NHID;
                if (fast) {
                    #pragma unroll
                    for (int kc = 0; kc < 16; ++kc) {
                        const _Float16* p = hrow + kc * 32 + g4 * 8;
                        asm volatile("global_load_dwordx4 %0, %1, off nt"
                                     : "=v"(Bf[kc]) : "v"(p));
                    }
                } else {
                    #pragma unroll
                    for (int kc = 0; kc < 16; ++kc) {
                        const _Float16* p = hrow + kc * 32 + g4 * 8;
                        asm volatile("global_load_dwordx4 %0, %1, off sc0 sc1"
                                     : "=v"(Bf[kc]) : "v"(p));
                    }
                }
                asm volatile("s_waitcnt vmcnt(0)" ::: "memory");
                __builtin_amdgcn_sched_barrier(0);
            }
            // -- 3. gh MFMA, Whh fragments streamed from LDS
            f32x4 a0 = {0.f,0.f,0.f,0.f}, a1 = a0, a2 = a0;
            #pragma unroll
            for (int kc = 0; kc < 16; ++kc) {
                f16x8 w0 = *(const f16x8*)&fragWhh[0][kc][lane][0];
                f16x8 w1 = *(const f16x8*)&fragWhh[1][kc][lane][0];
                f16x8 w2 = *(const f16x8*)&fragWhh[2][kc][lane][0];
                a0 = __builtin_amdgcn_mfma_f32_16x16x32_f16(w0, Bf[kc], a0, 0, 0, 0);
                a1 = __builtin_amdgcn_mfma_f32_16x16x32_f16(w1, Bf[kc], a1, 0, 0, 0);
                a2 = __builtin_amdgcn_mfma_f32_16x16x32_f16(w2, Bf[kc], a2, 0, 0, 0);
            }
            // -- 4. gi ready? read it, release the parity slot
            while (vseq[half] < (unsigned)(t + 1)) { }
            const int par = t & 1;
            f32x4 gr = *(const f32x4*)&gi_lds[par][half][0][r15][g4 * 4];
            f32x4 gz = *(const f32x4*)&gi_lds[par][half][1][r15][g4 * 4];
            f32x4 gn = *(const f32x4*)&gi_lds[par][half][2][r15][g4 * 4];
            f32x4 gd = *(const f32x4*)&gi_lds[par][half][3][r15][g4 * 4];
            asm volatile("s_waitcnt lgkmcnt(0)" ::: "memory");
            if (lane == 0) vseq[2 + half] = (unsigned)(t + 1);
            // -- 5. gates in-register
            f32x4 hn, o;
            #pragma unroll
            for (int i = 0; i < 4; ++i) {
                float rr = 1.f / (1.f + __expf(-((gr[i] + bir[i]) + (a0[i] + bhr[i]))));
                float zz = 1.f / (1.f + __expf(-((gz[i] + biz[i]) + (a1[i] + bhz[i]))));
                float aa = (gn[i] + bin[i]) + rr * (a2[i] + bhn[i]);
                float nn = 1.f - 2.f / (__expf(2.f * aa) + 1.f);
                hn[i] = (1.f - zz) * nn + zz * hold[i];
                o[i]  = hn[i] + gd[i] + bd4[i];
            }
            hold = hn;
            // -- 6. h broadcast store (8B), drain, publish flag
            union { _Float16 h[4]; unsigned long long u; } cv;
            cv.h[0] = (_Float16)hn[0]; cv.h[1] = (_Float16)hn[1];
            cv.h[2] = (_Float16)hn[2]; cv.h[3] = (_Float16)hn[3];
            _Float16* hw = (((t + 1) & 1) ? g_hb1 : g_hb0) + (size_t)bg * NHID + ks + g4 * 4;
            if (fast) {
                *(unsigned long long*)hw = cv.u;
            } else {
                asm volatile("global_store_dwordx2 %0, %1, off sc0 sc1"
                             :: "v"(hw), "v"(cv.u) : "memory");
            }
            asm volatile("s_waitcnt vmcnt(0)" ::: "memory");
            if (lane == 0) {
                unsigned int* fp = &g_flags[w * 16 + half * 8];
                if (fast) *(volatile unsigned int*)fp = (unsigned)(t + 1);
                else __hip_atomic_store(fp, (unsigned)(t + 1), __ATOMIC_RELAXED,
                                        __HIP_MEMORY_SCOPE_AGENT);
            }
            // -- 7. out store (post-flag; drains in next step's shadow)
            *(f32x4*)(out + (size_t)t * (NB * NHID) + (size_t)bg * NHID + ks + g4 * 4) = o;
        }
        // h_last
        *(f32x4*)(out + (size_t)TT * (NB * NHID) + (size_t)bg * NHID + ks + g4 * 4) = hold;
        if (lane == 0)
            __hip_atomic_fetch_add(g_flags + 514, 1u, __ATOMIC_RELAXED,
                                   __HIP_MEMORY_SCOPE_AGENT);
    } else {
        // ================= PRODUCER (waves 2,3) =================
        __builtin_amdgcn_s_setprio(1);
        const float* Xrow = X + (size_t)bg * NI;

        #pragma unroll 1
        for (int tp = 0; tp < TT; ++tp) {
            while ((int)vseq[2 + half] < tp - 1) { }   // 2-deep gi throttle
            const float* xp = Xrow + (size_t)tp * (NB * NI);
            f16x8 Bf[16];
            #pragma unroll
            for (int kc = 0; kc < 16; ++kc) {
                const f32x4* p = (const f32x4*)(xp + kc * 32 + g4 * 8);
                Bf[kc] = pack8(p[0], p[1]);
            }
            f32x4 acc[4];
            #pragma unroll
            for (int q = 0; q < 4; ++q) acc[q] = (f32x4){0.f, 0.f, 0.f, 0.f};
            #pragma unroll
            for (int mat = 0; mat < 4; ++mat) {
                f16x8 wb[16];
                #pragma unroll
                for (int kc = 0; kc < 16; ++kc)
                    wb[kc] = *(const f16x8*)&g_wfrag[w][mat][kc][lane][0];
                #pragma unroll
                for (int kc = 0; kc < 16; ++kc)
                    acc[mat] = __builtin_amdgcn_mfma_f32_16x16x32_f16(wb[kc], Bf[kc], acc[mat], 0, 0, 0);
            }
            const int par = tp & 1;
            *(f32x4*)&gi_lds[par][half][0][r15][g4 * 4] = acc[0];
            *(f32x4*)&gi_lds[par][half][1][r15][g4 * 4] = acc[1];
            *(f32x4*)&gi_lds[par][half][2][r15][g4 * 4] = acc[2];
            *(f32x4*)&gi_lds[par][half][3][r15][g4 * 4] = acc[3];
            asm volatile("s_waitcnt lgkmcnt(0)" ::: "memory");
            if (lane == 0) vseq[half] = (unsigned)(tp + 1);
        }
    }
}

extern "C" void kernel_launch(void* const* d_in, const int* in_sizes, int n_in,
                              void* d_out, int out_size, void* d_ws, size_t ws_size,
                              hipStream_t stream) {
    const float* X   = (const float*)d_in[0];
    const float* h0  = (const float*)d_in[1];
    const float* Wih = (const float*)d_in[2];
    const float* Whh = (const float*)d_in[3];
    const float* bih = (const float*)d_in[4];
    const float* bhh = (const float*)d_in[5];
    const float* Wd  = (const float*)d_in[6];
    const float* bd  = (const float*)d_in[7];
    float* out = (float*)d_out;

    init_flags_k<<<dim3(1), dim3(256), 0, stream>>>();
    pack_wfrag_k<<<dim3(NWG), dim3(256), 0, stream>>>(Wih, Wd);

    gru_persist<<<dim3(512), dim3(256), 0, stream>>>(
        X, h0, Wih, Whh, bih, bhh, Wd, bd, out);
}